// Round 4
// baseline (1642.847 us; speedup 1.0000x reference)
//
#include <hip/hip_runtime.h>
#include <hip/hip_bf16.h>

// 2-layer 4-direction MDLSTM, fused. B=256, Wd=2048, OUT=11.
// One block per batch (256 threads = 4 waves). Wave d runs direction d's
// recurrence for BOTH layers; lane j<11 owns unit j and computes all 4 live
// gates (i,f_w,o,a) as two float2 packed dots (v_pk_fma_f32).
//
// Serial-chain rule learned R3: NO LDS crossbar ops on the chain.
//  - h broadcast: 11 v_readlane (wave-uniform source lane) -> VALU only.
//  - L1 input: 1 wave-uniform ds_read (prefetched, off-chain).
//  - L2 input: 3 wave-uniform ds_read_b128 of the padded acc row
//    (prefetched 2 steps ahead, off-chain).
//  - L1 dir-sum: ds_add_f32 into acc (no return, off-chain).
//  - L2 dir-sum: global_atomic_add_f32 straight into out[b][j][w]
//    (no return, off-chain; d_out pre-zeroed by hipMemsetAsync).
// LDS: acc 2048x12 fp32 (96 KB, L1 accumulator == L2 input) + xw 8 KB.

#define NOUT 11
#define WD 2048
#define NB 256
#define ROW 12              // padded acc row (12 floats = 48 B, b128-aligned)
#define ACCN (WD * ROW)

typedef float f2 __attribute__((ext_vector_type(2)));
typedef float f4 __attribute__((ext_vector_type(4)));

__device__ __forceinline__ float rl(float v, int l) {
  return __int_as_float(__builtin_amdgcn_readlane(__float_as_int(v), l));
}
__device__ __forceinline__ f2 fma2(float s, f2 w, f2 a) {
  f2 sv = {s, s};
  return __builtin_elementwise_fma(sv, w, a);
}
__device__ __forceinline__ f2 mul2(float s, f2 w) {
  f2 sv = {s, s};
  return sv * w;
}
__device__ __forceinline__ float sigm(float x) {
  return __builtin_amdgcn_rcpf(1.0f + __expf(-x));
}
__device__ __forceinline__ float tanh_(float x) {
  return fmaf(2.0f, __builtin_amdgcn_rcpf(1.0f + __expf(-2.0f * x)), -1.0f);
}

// 11-term packed dot with 2 accumulator chains (chain depth 6)
#define UDOT(H0,H1,H2,H3,H4,H5,H6,H7,H8,H9,H10, UA, UB, giA, giB, gA, gB)  \
  f2 gA##0 = fma2(H0, UA[0], giA);                                          \
  f2 gA##1 = mul2(H1, UA[1]);                                               \
  f2 gB##0 = fma2(H0, UB[0], giB);                                          \
  f2 gB##1 = mul2(H1, UB[1]);                                               \
  gA##0 = fma2(H2, UA[2], gA##0);  gA##1 = fma2(H3, UA[3], gA##1);          \
  gB##0 = fma2(H2, UB[2], gB##0);  gB##1 = fma2(H3, UB[3], gB##1);          \
  gA##0 = fma2(H4, UA[4], gA##0);  gA##1 = fma2(H5, UA[5], gA##1);          \
  gB##0 = fma2(H4, UB[4], gB##0);  gB##1 = fma2(H5, UB[5], gB##1);          \
  gA##0 = fma2(H6, UA[6], gA##0);  gA##1 = fma2(H7, UA[7], gA##1);          \
  gB##0 = fma2(H6, UB[6], gB##0);  gB##1 = fma2(H7, UB[7], gB##1);          \
  gA##0 = fma2(H8, UA[8], gA##0);  gA##1 = fma2(H9, UA[9], gA##1);          \
  gB##0 = fma2(H8, UB[8], gB##0);  gB##1 = fma2(H9, UB[9], gB##1);          \
  gA##0 = fma2(H10, UA[10], gA##0);                                         \
  gB##0 = fma2(H10, UB[10], gB##0);                                         \
  const f2 gA = gA##0 + gA##1, gB = gB##0 + gB##1;

__global__ __launch_bounds__(256, 1) void mdlstm_fused(
    const float* __restrict__ x, const float* __restrict__ W0,
    const float* __restrict__ U0, const float* __restrict__ b0,
    const float* __restrict__ W1, const float* __restrict__ U1,
    const float* __restrict__ b1, float* __restrict__ out) {
  __shared__ __align__(16) float acc[ACCN];  // 96 KB
  __shared__ __align__(16) float xw[WD];     // 8 KB

  const int tid = threadIdx.x;
  const int b = blockIdx.x;

  // ---- Phase A: height-sum x -> xw (f4 vectorized); zero acc ----
  {
    const f4* xb4 = (const f4*)(x + (size_t)b * 32 * WD);
    f4* xw4 = (f4*)xw;
    for (int w = tid; w < WD / 4; w += 256) {
      f4 s = xb4[w];
#pragma unroll
      for (int h = 1; h < 32; ++h) s += xb4[h * (WD / 4) + w];
      xw4[w] = s;
    }
    f4* a4 = (f4*)acc;
    const f4 z = {0.f, 0.f, 0.f, 0.f};
    for (int i = tid; i < ACCN / 4; i += 256) a4[i] = z;
  }
  __syncthreads();

  const int lane = tid & 63;
  const int d = tid >> 6;            // wave id == direction
  const bool fwd = ((d & 1) == 0);
  const int j = lane;

  // ---- Phase B: layer-1 scan (each wave: its direction; lanes 0..10) ----
  if (lane < NOUT) {
    const int ic = j, fc = 11 + j, oc = 33 + j, ac = 44 + j;
    f2 U2A[NOUT], U2B[NOUT];
#pragma unroll
    for (int s = 0; s < NOUT; ++s) {
      const float* Up = U0 + (d * NOUT + s) * 55;
      U2A[s] = (f2){Up[ic], Up[fc]};
      U2B[s] = (f2){Up[oc], Up[ac]};
    }
    const float* Wp = W0 + d * 55;
    const f2 w2A = {Wp[ic], Wp[fc]}, w2B = {Wp[oc], Wp[ac]};
    const float* bp = b0 + d * 55;
    const f2 b2A = {bp[ic], bp[fc]}, b2B = {bp[oc], bp[ac]};

    int xo = fwd ? 0 : (WD - 1);
    const int xd = fwd ? 1 : -1;
    int ao = (fwd ? 0 : (WD - 1) * ROW) + j;
    const int ad = fwd ? ROW : -ROW;

    float hj = 0.f, cj = 0.f;
    float xv = xw[xo];
    xo += xd;
    f2 giA = {fmaf(xv, w2A.x, b2A.x), fmaf(xv, w2A.y, b2A.y)};
    f2 giB = {fmaf(xv, w2B.x, b2B.x), fmaf(xv, w2B.y, b2B.y)};

    for (int t = 0; t < WD; ++t) {
      // chain head: h broadcast via readlane (VALU only)
      const float h0 = rl(hj, 0), h1 = rl(hj, 1), h2 = rl(hj, 2),
                  h3 = rl(hj, 3), h4 = rl(hj, 4), h5 = rl(hj, 5),
                  h6 = rl(hj, 6), h7 = rl(hj, 7), h8 = rl(hj, 8),
                  h9 = rl(hj, 9), h10 = rl(hj, 10);
      // off-chain: prefetch next input
      const float xvn = xw[xo & (WD - 1)];
      xo += xd;
      UDOT(h0, h1, h2, h3, h4, h5, h6, h7, h8, h9, h10, U2A, U2B, giA, giB,
           gA, gB)
      const float iv = sigm(gA.x), fv = sigm(gA.y);
      const float ov = sigm(gB.x), av = tanh_(gB.y);
      cj = fmaf(fv, cj, iv * av);
      hj = ov * tanh_(cj);
      atomicAdd(&acc[ao], hj);  // ds_add_f32, no return, off-chain
      ao += ad;
      // off-chain: next input stage
      giA = (f2){fmaf(xvn, w2A.x, b2A.x), fmaf(xvn, w2A.y, b2A.y)};
      giB = (f2){fmaf(xvn, w2B.x, b2B.x), fmaf(xvn, w2B.y, b2B.y)};
    }
  }
  __syncthreads();

  // ---- Phase C: layer-2 scan; y = acc rows; out via global atomics ----
  if (lane < NOUT) {
    const int ic = j, fc = 11 + j, oc = 33 + j, ac = 44 + j;
    f2 U2A[NOUT], U2B[NOUT], W2A[NOUT], W2B[NOUT];
#pragma unroll
    for (int s = 0; s < NOUT; ++s) {
      const float* Up = U1 + (d * NOUT + s) * 55;
      U2A[s] = (f2){Up[ic], Up[fc]};
      U2B[s] = (f2){Up[oc], Up[ac]};
      const float* Wp = W1 + (d * NOUT + s) * 55;
      W2A[s] = (f2){Wp[ic], Wp[fc]};
      W2B[s] = (f2){Wp[oc], Wp[ac]};
    }
    const float* bp = b1 + d * 55;
    const f2 b2A = {bp[ic], bp[fc]}, b2B = {bp[oc], bp[ac]};

    const f4* accv = (const f4*)acc;
    const int qd = fwd ? 3 : -3;           // row stride in f4 units (ROW/4)
    const int qmax = 3 * (WD - 1);
    int q = fwd ? 0 : qmax;

    // input stage for t=0; prefetch row t=1
    f4 c0 = accv[q], c1 = accv[q + 1], c2 = accv[q + 2];
    q += qd;
    int qc = q < 0 ? 0 : (q > qmax ? qmax : q);
    f4 p0 = accv[qc], p1 = accv[qc + 1], p2 = accv[qc + 2];
    q += qd;

    auto GI = [&](const f4& r0, const f4& r1, const f4& r2, f2& giA, f2& giB) {
      f2 A = fma2(r0.x, W2A[0], b2A), B = fma2(r0.x, W2B[0], b2B);
      A = fma2(r0.y, W2A[1], A);  B = fma2(r0.y, W2B[1], B);
      A = fma2(r0.z, W2A[2], A);  B = fma2(r0.z, W2B[2], B);
      A = fma2(r0.w, W2A[3], A);  B = fma2(r0.w, W2B[3], B);
      A = fma2(r1.x, W2A[4], A);  B = fma2(r1.x, W2B[4], B);
      A = fma2(r1.y, W2A[5], A);  B = fma2(r1.y, W2B[5], B);
      A = fma2(r1.z, W2A[6], A);  B = fma2(r1.z, W2B[6], B);
      A = fma2(r1.w, W2A[7], A);  B = fma2(r1.w, W2B[7], B);
      A = fma2(r2.x, W2A[8], A);  B = fma2(r2.x, W2B[8], B);
      A = fma2(r2.y, W2A[9], A);  B = fma2(r2.y, W2B[9], B);
      A = fma2(r2.z, W2A[10], A); B = fma2(r2.z, W2B[10], B);
      giA = A; giB = B;
    };

    f2 giA, giB;
    GI(c0, c1, c2, giA, giB);

    float* op = out + (size_t)b * (NOUT * WD) + j * WD + (fwd ? 0 : WD - 1);
    const int od = fwd ? 1 : -1;

    float hj = 0.f, cj = 0.f;
    for (int t = 0; t < WD; ++t) {
      const float h0 = rl(hj, 0), h1 = rl(hj, 1), h2 = rl(hj, 2),
                  h3 = rl(hj, 3), h4 = rl(hj, 4), h5 = rl(hj, 5),
                  h6 = rl(hj, 6), h7 = rl(hj, 7), h8 = rl(hj, 8),
                  h9 = rl(hj, 9), h10 = rl(hj, 10);
      // off-chain: prefetch row t+2
      int qc2 = q < 0 ? 0 : (q > qmax ? qmax : q);
      const f4 n0 = accv[qc2], n1 = accv[qc2 + 1], n2 = accv[qc2 + 2];
      q += qd;
      UDOT(h0, h1, h2, h3, h4, h5, h6, h7, h8, h9, h10, U2A, U2B, giA, giB,
           gA, gB)
      const float iv = sigm(gA.x), fv = sigm(gA.y);
      const float ov = sigm(gB.x), av = tanh_(gB.y);
      cj = fmaf(fv, cj, iv * av);
      hj = ov * tanh_(cj);
      unsafeAtomicAdd(op, hj);  // global_atomic_add_f32, no return, off-chain
      op += od;
      // off-chain: input stage for t+1, rotate prefetch regs
      GI(p0, p1, p2, giA, giB);
      p0 = n0; p1 = n1; p2 = n2;
    }
  }
}

extern "C" void kernel_launch(void* const* d_in, const int* in_sizes, int n_in,
                              void* d_out, int out_size, void* d_ws,
                              size_t ws_size, hipStream_t stream) {
  const float* x  = (const float*)d_in[0];
  const float* W0 = (const float*)d_in[1];
  const float* U0 = (const float*)d_in[2];
  const float* b0 = (const float*)d_in[3];
  const float* W1 = (const float*)d_in[4];
  const float* U1 = (const float*)d_in[5];
  const float* b1 = (const float*)d_in[6];
  float* out = (float*)d_out;

  hipMemsetAsync(d_out, 0, (size_t)out_size * sizeof(float), stream);
  mdlstm_fused<<<NB, 256, 0, stream>>>(x, W0, U0, b0, W1, U1, b1, out);
}

// Round 5
// 980.878 us; speedup vs baseline: 1.6749x; 1.6749x over previous
//
#include <hip/hip_runtime.h>
#include <hip/hip_bf16.h>

// 2-layer 4-direction MDLSTM, fused, one dispatch. B=256, Wd=2048, OUT=11.
// One block per batch (4 waves; wave d = direction d for both layers).
// Lane j<11 owns unit j, computing all 4 live gates (i,f_w,o,a) as two
// float2 packed dots (v_pk_fma_f32).
//
// Serial-chain rules (learned R3/R4):
//  - NO LDS crossbar ops on the chain: h broadcast = 11 v_readlane.
//  - NO scattered global atomics: direction-sums go to LDS ds_add_f32
//    (conflict-free, no-return, off-chain); out written by plain stores.
//  - All input reads wave-uniform ds_read, prefetched 2 steps ahead.
// LDS: acc fp32 2048x12 (96 KB; L1 dir-sum, then L2 dir-sum) +
//      ybf 2048x6 u32 (48 KB; xw fp32 strip during L1, bf16 y-strip for L2).

#define NOUT 11
#define WD 2048
#define NB 256
#define ROW 12               // acc row: 12 fp32 (48 B); slot 11 = zero pad
#define ACCN (WD * ROW)
#define YW 6                 // ybf row: 6 u32 = 12 bf16

typedef float f2 __attribute__((ext_vector_type(2)));
typedef float f4 __attribute__((ext_vector_type(4)));
typedef unsigned int u32;
typedef u32 u2 __attribute__((ext_vector_type(2)));

__device__ __forceinline__ float rl(float v, int l) {
  return __int_as_float(__builtin_amdgcn_readlane(__float_as_int(v), l));
}
__device__ __forceinline__ f2 fma2(float s, f2 w, f2 a) {
  f2 sv = {s, s};
  return __builtin_elementwise_fma(sv, w, a);
}
__device__ __forceinline__ f2 mul2(float s, f2 w) {
  f2 sv = {s, s};
  return sv * w;
}
__device__ __forceinline__ float sigm(float x) {
  return __builtin_amdgcn_rcpf(1.0f + __expf(-x));
}
__device__ __forceinline__ float tanh_(float x) {
  return fmaf(2.0f, __builtin_amdgcn_rcpf(1.0f + __expf(-2.0f * x)), -1.0f);
}
// bf16 helpers (RNE pack; unpack = shift/and, 1 VALU op each)
__device__ __forceinline__ u32 bfbits(float f) {
  u32 x = __float_as_uint(f);
  return (x + 0x7fffu + ((x >> 16) & 1u)) >> 16;
}
__device__ __forceinline__ float bflo(u32 u) { return __uint_as_float(u << 16); }
__device__ __forceinline__ float bfhi(u32 u) {
  return __uint_as_float(u & 0xffff0000u);
}

// 11-term packed dot, 2 accumulator chains per gate-pair (chain depth 6)
#define UDOT(H0,H1,H2,H3,H4,H5,H6,H7,H8,H9,H10, UA, UB, giA, giB, gA, gB)  \
  f2 gA##0 = fma2(H0, UA[0], giA);                                          \
  f2 gA##1 = mul2(H1, UA[1]);                                               \
  f2 gB##0 = fma2(H0, UB[0], giB);                                          \
  f2 gB##1 = mul2(H1, UB[1]);                                               \
  gA##0 = fma2(H2, UA[2], gA##0);  gA##1 = fma2(H3, UA[3], gA##1);          \
  gB##0 = fma2(H2, UB[2], gB##0);  gB##1 = fma2(H3, UB[3], gB##1);          \
  gA##0 = fma2(H4, UA[4], gA##0);  gA##1 = fma2(H5, UA[5], gA##1);          \
  gB##0 = fma2(H4, UB[4], gB##0);  gB##1 = fma2(H5, UB[5], gB##1);          \
  gA##0 = fma2(H6, UA[6], gA##0);  gA##1 = fma2(H7, UA[7], gA##1);          \
  gB##0 = fma2(H6, UB[6], gB##0);  gB##1 = fma2(H7, UB[7], gB##1);          \
  gA##0 = fma2(H8, UA[8], gA##0);  gA##1 = fma2(H9, UA[9], gA##1);          \
  gB##0 = fma2(H8, UB[8], gB##0);  gB##1 = fma2(H9, UB[9], gB##1);          \
  gA##0 = fma2(H10, UA[10], gA##0);                                         \
  gB##0 = fma2(H10, UB[10], gB##0);                                         \
  const f2 gA = gA##0 + gA##1, gB = gB##0 + gB##1;

__global__ __launch_bounds__(256, 1) void mdlstm_fused(
    const float* __restrict__ x, const float* __restrict__ W0,
    const float* __restrict__ U0, const float* __restrict__ b0,
    const float* __restrict__ W1, const float* __restrict__ U1,
    const float* __restrict__ b1, float* __restrict__ out) {
  __shared__ __align__(16) float acc[ACCN];  // 96 KB
  __shared__ __align__(16) u32 ybf[WD * YW]; // 48 KB (xw | y-bf16)

  const int tid = threadIdx.x;
  const int b = blockIdx.x;
  float* xw = (float*)ybf;  // 8 KB, live during phases A/B only

  // ---- Phase A: height-sum x -> xw (f4); zero acc ----
  {
    const f4* xb4 = (const f4*)(x + (size_t)b * 32 * WD);
    f4* xw4 = (f4*)xw;
    for (int w = tid; w < WD / 4; w += 256) {
      f4 s = xb4[w];
#pragma unroll
      for (int h = 1; h < 32; ++h) s += xb4[h * (WD / 4) + w];
      xw4[w] = s;
    }
    f4* a4 = (f4*)acc;
    const f4 z = {0.f, 0.f, 0.f, 0.f};
    for (int i = tid; i < ACCN / 4; i += 256) a4[i] = z;
  }
  __syncthreads();

  const int lane = tid & 63;
  const int d = tid >> 6;  // wave id == direction
  const bool fwd = ((d & 1) == 0);
  const int j = lane;

  // ---- Phase B: layer-1 scan ----
  if (lane < NOUT) {
    const int ic = j, fc = 11 + j, oc = 33 + j, ac = 44 + j;
    f2 U2A[NOUT], U2B[NOUT];
#pragma unroll
    for (int s = 0; s < NOUT; ++s) {
      const float* Up = U0 + (d * NOUT + s) * 55;
      U2A[s] = (f2){Up[ic], Up[fc]};
      U2B[s] = (f2){Up[oc], Up[ac]};
    }
    const float* Wp = W0 + d * 55;
    const f2 w2A = {Wp[ic], Wp[fc]}, w2B = {Wp[oc], Wp[ac]};
    const float* bp = b0 + d * 55;
    const f2 b2A = {bp[ic], bp[fc]}, b2B = {bp[oc], bp[ac]};

    int xo = fwd ? 0 : (WD - 1);
    const int xd = fwd ? 1 : -1;
    int ao = (fwd ? 0 : (WD - 1) * ROW) + j;
    const int ad = fwd ? ROW : -ROW;

    float hj = 0.f, cj = 0.f;
    const float xc = xw[xo];             // t=0 input
    xo += xd;
    f2 giA = {fmaf(xc, w2A.x, b2A.x), fmaf(xc, w2A.y, b2A.y)};
    f2 giB = {fmaf(xc, w2B.x, b2B.x), fmaf(xc, w2B.y, b2B.y)};
    float xn = xw[xo & (WD - 1)];        // t=1 input, in flight
    xo += xd;

    for (int t = 0; t < WD; ++t) {
      const float h0 = rl(hj, 0), h1 = rl(hj, 1), h2 = rl(hj, 2),
                  h3 = rl(hj, 3), h4 = rl(hj, 4), h5 = rl(hj, 5),
                  h6 = rl(hj, 6), h7 = rl(hj, 7), h8 = rl(hj, 8),
                  h9 = rl(hj, 9), h10 = rl(hj, 10);
      const float xn2 = xw[xo & (WD - 1)];  // prefetch t+2 (off-chain)
      xo += xd;
      UDOT(h0, h1, h2, h3, h4, h5, h6, h7, h8, h9, h10, U2A, U2B, giA, giB,
           gA, gB)
      const float iv = sigm(gA.x), fv = sigm(gA.y);
      const float ov = sigm(gB.x), av = tanh_(gB.y);
      cj = fmaf(fv, cj, iv * av);
      hj = ov * tanh_(cj);
      atomicAdd(&acc[ao], hj);  // ds_add_f32, no-return, off-chain
      ao += ad;
      giA = (f2){fmaf(xn, w2A.x, b2A.x), fmaf(xn, w2A.y, b2A.y)};
      giB = (f2){fmaf(xn, w2B.x, b2B.x), fmaf(xn, w2B.y, b2B.y)};
      xn = xn2;
    }
  }
  __syncthreads();

  // ---- Phase C: pack acc -> bf16 ybf (xw now dead); then re-zero acc ----
  for (int i = tid; i < WD * YW; i += 256) {
    const int w = i / YW;
    const int e = (i - w * YW) * 2;
    const float a0 = acc[w * ROW + e];
    const float a1 = acc[w * ROW + e + 1];  // e+1==11 -> zero pad slot
    ybf[i] = bfbits(a0) | (bfbits(a1) << 16);
  }
  __syncthreads();
  {
    f4* a4 = (f4*)acc;
    const f4 z = {0.f, 0.f, 0.f, 0.f};
    for (int i = tid; i < ACCN / 4; i += 256) a4[i] = z;
  }
  __syncthreads();

  // ---- Phase D: layer-2 scan ----
  if (lane < NOUT) {
    const int ic = j, fc = 11 + j, oc = 33 + j, ac = 44 + j;
    f2 U2A[NOUT], U2B[NOUT], W2A[NOUT], W2B[NOUT];
#pragma unroll
    for (int s = 0; s < NOUT; ++s) {
      const float* Up = U1 + (d * NOUT + s) * 55;
      U2A[s] = (f2){Up[ic], Up[fc]};
      U2B[s] = (f2){Up[oc], Up[ac]};
      const float* Wp = W1 + (d * NOUT + s) * 55;
      W2A[s] = (f2){Wp[ic], Wp[fc]};
      W2B[s] = (f2){Wp[oc], Wp[ac]};
    }
    const float* bp = b1 + d * 55;
    const f2 b2A = {bp[ic], bp[fc]}, b2B = {bp[oc], bp[ac]};

    const u2* yv = (const u2*)ybf;     // row t -> yv[3t .. 3t+2]
    const int qd = fwd ? 3 : -3;
    const int qmax = 3 * (WD - 1);
    int q = fwd ? 0 : qmax;

    // input stage t=0; prefetch row t=1
    u2 c0 = yv[q], c1 = yv[q + 1], c2 = yv[q + 2];
    q += qd;
    const int qc1 = q < 0 ? 0 : (q > qmax ? qmax : q);
    u2 p0 = yv[qc1], p1 = yv[qc1 + 1], p2 = yv[qc1 + 2];
    q += qd;

    auto GI = [&](u2 r0, u2 r1, u2 r2, f2& oA, f2& oB) {
      const float y0 = bflo(r0.x), y1 = bfhi(r0.x), y2 = bflo(r0.y),
                  y3 = bfhi(r0.y), y4 = bflo(r1.x), y5 = bfhi(r1.x),
                  y6 = bflo(r1.y), y7 = bfhi(r1.y), y8 = bflo(r2.x),
                  y9 = bfhi(r2.x), y10 = bflo(r2.y);
      f2 A = fma2(y0, W2A[0], b2A), B = fma2(y0, W2B[0], b2B);
      A = fma2(y1, W2A[1], A);   B = fma2(y1, W2B[1], B);
      A = fma2(y2, W2A[2], A);   B = fma2(y2, W2B[2], B);
      A = fma2(y3, W2A[3], A);   B = fma2(y3, W2B[3], B);
      A = fma2(y4, W2A[4], A);   B = fma2(y4, W2B[4], B);
      A = fma2(y5, W2A[5], A);   B = fma2(y5, W2B[5], B);
      A = fma2(y6, W2A[6], A);   B = fma2(y6, W2B[6], B);
      A = fma2(y7, W2A[7], A);   B = fma2(y7, W2B[7], B);
      A = fma2(y8, W2A[8], A);   B = fma2(y8, W2B[8], B);
      A = fma2(y9, W2A[9], A);   B = fma2(y9, W2B[9], B);
      A = fma2(y10, W2A[10], A); B = fma2(y10, W2B[10], B);
      oA = A;
      oB = B;
    };

    f2 giA, giB;
    GI(c0, c1, c2, giA, giB);

    int ao = (fwd ? 0 : (WD - 1) * ROW) + j;
    const int ad = fwd ? ROW : -ROW;

    float hj = 0.f, cj = 0.f;
    for (int t = 0; t < WD; ++t) {
      const float h0 = rl(hj, 0), h1 = rl(hj, 1), h2 = rl(hj, 2),
                  h3 = rl(hj, 3), h4 = rl(hj, 4), h5 = rl(hj, 5),
                  h6 = rl(hj, 6), h7 = rl(hj, 7), h8 = rl(hj, 8),
                  h9 = rl(hj, 9), h10 = rl(hj, 10);
      // prefetch row t+2 (off-chain)
      const int qc = q < 0 ? 0 : (q > qmax ? qmax : q);
      const u2 n0 = yv[qc], n1 = yv[qc + 1], n2 = yv[qc + 2];
      q += qd;
      UDOT(h0, h1, h2, h3, h4, h5, h6, h7, h8, h9, h10, U2A, U2B, giA, giB,
           gA, gB)
      const float iv = sigm(gA.x), fv = sigm(gA.y);
      const float ov = sigm(gB.x), av = tanh_(gB.y);
      cj = fmaf(fv, cj, iv * av);
      hj = ov * tanh_(cj);
      atomicAdd(&acc[ao], hj);  // ds_add_f32, no-return, off-chain
      ao += ad;
      GI(p0, p1, p2, giA, giB);  // input stage for t+1 (off-chain)
      p0 = n0; p1 = n1; p2 = n2;
    }
  }
  __syncthreads();

  // ---- Phase E: writeout out[b][j][w] = acc[w*ROW+j], coalesced in w ----
  float* ob = out + (size_t)b * (NOUT * WD);
  for (int i = tid; i < NOUT * WD; i += 256) {
    const int jj = i >> 11;       // i / WD
    const int w = i & (WD - 1);   // i % WD
    ob[i] = acc[w * ROW + jj];
  }
}

extern "C" void kernel_launch(void* const* d_in, const int* in_sizes, int n_in,
                              void* d_out, int out_size, void* d_ws,
                              size_t ws_size, hipStream_t stream) {
  const float* x  = (const float*)d_in[0];
  const float* W0 = (const float*)d_in[1];
  const float* U0 = (const float*)d_in[2];
  const float* b0 = (const float*)d_in[3];
  const float* W1 = (const float*)d_in[4];
  const float* U1 = (const float*)d_in[5];
  const float* b1 = (const float*)d_in[6];
  float* out = (float*)d_out;

  mdlstm_fused<<<NB, 256, 0, stream>>>(x, W0, U0, b0, W1, U1, b1, out);
}

// Round 6
// 734.140 us; speedup vs baseline: 2.2378x; 1.3361x over previous
//
#include <hip/hip_runtime.h>
#include <hip/hip_bf16.h>

// 2-layer 4-direction MDLSTM, fused, one dispatch. B=256, Wd=2048, OUT=11.
// One block per batch (4 waves; wave d = direction d). QUAD lane layout:
// lane t = 4*j + cls (t<44): quad j holds gate classes (i,f_w,o,a) of unit j.
//  - UDOT: 11 scalar v_fma per lane (own column) — 4x useful lanes vs R5.
//  - Shared activation: a-gate's 2x folded into weights; act = kA*sg + kB
//    with per-lane (kA,kB). One exp/rcp path for all classes.
//  - Cross-class gather: 4 v_mov_dpp quad_perm (VALU; no LDS crossbar).
//  - h-broadcast: 11 v_readlane (lane 4s) — wave-uniform SGPRs.
//  - Dir-sum: cls0-masked ds_add_f32 into LDS acc (no global atomics).
//  - Inputs: wave-uniform LDS reads, prefetched 2 steps ahead, off-chain.
// LDS: acc fp32 2048x12 (96 KB) + ybf 2048x6 u32 (48 KB; xw | y1-bf16).

#define NOUT 11
#define WD 2048
#define NB 256
#define ROW 12               // acc row: 12 fp32; slot 11 stays zero
#define ACCN (WD * ROW)
#define YW 6                 // ybf row: 6 u32 = 12 bf16

typedef float f4 __attribute__((ext_vector_type(4)));
typedef unsigned int u32;
typedef u32 u2 __attribute__((ext_vector_type(2)));

__device__ __forceinline__ float rl(float v, int l) {
  return __int_as_float(__builtin_amdgcn_readlane(__float_as_int(v), l));
}
template <int CTRL>
__device__ __forceinline__ float qperm(float v) {
  return __int_as_float(__builtin_amdgcn_update_dpp(
      __float_as_int(v), __float_as_int(v), CTRL, 0xF, 0xF, false));
}
__device__ __forceinline__ float rcp_(float x) {
  return __builtin_amdgcn_rcpf(x);
}
__device__ __forceinline__ float tanh_(float x) {
  return fmaf(2.0f, rcp_(1.0f + __expf(-2.0f * x)), -1.0f);
}
// bf16 helpers (RNE)
__device__ __forceinline__ u32 bfbits(float f) {
  u32 x = __float_as_uint(f);
  return (x + 0x7fffu + ((x >> 16) & 1u)) >> 16;
}
__device__ __forceinline__ float bflo(u32 u) { return __uint_as_float(u << 16); }
__device__ __forceinline__ float bfhi(u32 u) {
  return __uint_as_float(u & 0xffff0000u);
}

// 11-term scalar dot, 2 chains, seeded by gi
#define UDOT(gi, g)                                                \
  float g##a = fmaf(h0, Uc[0], gi);                                \
  float g##b = h1 * Uc[1];                                         \
  g##a = fmaf(h2, Uc[2], g##a);   g##b = fmaf(h3, Uc[3], g##b);    \
  g##a = fmaf(h4, Uc[4], g##a);   g##b = fmaf(h5, Uc[5], g##b);    \
  g##a = fmaf(h6, Uc[6], g##a);   g##b = fmaf(h7, Uc[7], g##b);    \
  g##a = fmaf(h8, Uc[8], g##a);   g##b = fmaf(h9, Uc[9], g##b);    \
  g##a = fmaf(h10, Uc[10], g##a);                                  \
  const float g = g##a + g##b;

#define READLANES                                                      \
  const float h0 = rl(hj, 0), h1 = rl(hj, 4), h2 = rl(hj, 8),          \
              h3 = rl(hj, 12), h4 = rl(hj, 16), h5 = rl(hj, 20),       \
              h6 = rl(hj, 24), h7 = rl(hj, 28), h8 = rl(hj, 32),       \
              h9 = rl(hj, 36), h10 = rl(hj, 40);

#define STEP_TAIL(g)                                                   \
  const float sg = rcp_(1.0f + __expf(-(g)));                          \
  const float act = fmaf(kA, sg, kB);                                  \
  const float iv = qperm<0x00>(act);                                   \
  const float fv = qperm<0x55>(act);                                   \
  const float ov = qperm<0xAA>(act);                                   \
  const float av = qperm<0xFF>(act);                                   \
  cj = fmaf(fv, cj, iv * av);                                          \
  hj = ov * tanh_(cj);                                                 \
  if (cls == 0) atomicAdd(&acc[ao], hj);                               \
  ao += ad;

__global__ __launch_bounds__(256, 1) void mdlstm_fused(
    const float* __restrict__ x, const float* __restrict__ W0,
    const float* __restrict__ U0, const float* __restrict__ b0,
    const float* __restrict__ W1, const float* __restrict__ U1,
    const float* __restrict__ b1, float* __restrict__ out) {
  __shared__ __align__(16) float acc[ACCN];   // 96 KB
  __shared__ __align__(16) u32 ybf[WD * YW];  // 48 KB (xw | y1-bf16)

  const int tid = threadIdx.x;
  const int b = blockIdx.x;
  float* xw = (float*)ybf;  // 8 KB, live phases A/B only

  // ---- Phase A: height-sum x -> xw; zero acc ----
  {
    const f4* xb4 = (const f4*)(x + (size_t)b * 32 * WD);
    f4* xw4 = (f4*)xw;
    for (int w = tid; w < WD / 4; w += 256) {
      f4 s = xb4[w];
#pragma unroll
      for (int h = 1; h < 32; ++h) s += xb4[h * (WD / 4) + w];
      xw4[w] = s;
    }
    f4* a4 = (f4*)acc;
    const f4 z = {0.f, 0.f, 0.f, 0.f};
    for (int i = tid; i < ACCN / 4; i += 256) a4[i] = z;
  }
  __syncthreads();

  const int lane = tid & 63;
  const int d = tid >> 6;  // wave == direction
  const bool fwd = ((d & 1) == 0);
  const int j = lane >> 2;        // unit
  const int cls = lane & 3;       // 0=i 1=f_w 2=o 3=a
  // column in the 55-wide gate dim; dead f_h block (22..32) skipped
  const int colb = (cls == 0) ? 0 : (cls == 1) ? 11 : (cls == 2) ? 33 : 44;
  const int col = colb + j;
  const float ws = (cls == 3) ? 2.0f : 1.0f;   // fold tanh's 2x into weights
  const float kA = (cls == 3) ? 2.0f : 1.0f;
  const float kB = (cls == 3) ? -1.0f : 0.0f;

  // ---- Phase B: layer-1 scan ----
  if (lane < 44) {
    float Uc[NOUT];
#pragma unroll
    for (int s = 0; s < NOUT; ++s) Uc[s] = U0[(d * NOUT + s) * 55 + col] * ws;
    const float Wc = W0[d * 55 + col] * ws;
    const float bc = b0[d * 55 + col] * ws;

    int xo = fwd ? 0 : (WD - 1);
    const int xd = fwd ? 1 : -1;
    int ao = (fwd ? 0 : (WD - 1) * ROW) + j;
    const int ad = fwd ? ROW : -ROW;

    float hj = 0.f, cj = 0.f;
    const float xc = xw[xo];
    xo += xd;
    float gi = fmaf(xc, Wc, bc);
    float xn = xw[xo & (WD - 1)];
    xo += xd;

    for (int t = 0; t < WD; ++t) {
      READLANES
      const float xn2 = xw[xo & (WD - 1)];  // prefetch t+2 (off-chain)
      xo += xd;
      UDOT(gi, g)
      STEP_TAIL(g)
      gi = fmaf(xn, Wc, bc);  // input stage t+1 (off-chain)
      xn = xn2;
    }
  }
  __syncthreads();

  // ---- Phase C: pack acc -> bf16 ybf; re-zero acc ----
  for (int i = tid; i < WD * YW; i += 256) {
    const int w = i / YW;
    const int e = (i - w * YW) * 2;
    const float a0 = acc[w * ROW + e];
    const float a1 = acc[w * ROW + e + 1];  // slot 11 stays zero
    ybf[i] = bfbits(a0) | (bfbits(a1) << 16);
  }
  __syncthreads();
  {
    f4* a4 = (f4*)acc;
    const f4 z = {0.f, 0.f, 0.f, 0.f};
    for (int i = tid; i < ACCN / 4; i += 256) a4[i] = z;
  }
  __syncthreads();

  // ---- Phase D: layer-2 scan ----
  if (lane < 44) {
    float Uc[NOUT], Wc2[NOUT];
#pragma unroll
    for (int s = 0; s < NOUT; ++s) {
      Uc[s] = U1[(d * NOUT + s) * 55 + col] * ws;
      Wc2[s] = W1[(d * NOUT + s) * 55 + col] * ws;
    }
    const float bc = b1[d * 55 + col] * ws;

    const u2* yv = (const u2*)ybf;  // row t -> yv[3t..3t+2]
    const int qd = fwd ? 3 : -3;
    const int qmax = 3 * (WD - 1);
    int q = fwd ? 0 : qmax;

    // rows t=0 (current) and t=1 (pending regs)
    u2 c0 = yv[q], c1 = yv[q + 1], c2 = yv[q + 2];
    q += qd;
    const int qc1 = q < 0 ? 0 : (q > qmax ? qmax : q);
    u2 p0 = yv[qc1], p1 = yv[qc1 + 1], p2 = yv[qc1 + 2];
    q += qd;

    auto GI = [&](u2 r0, u2 r1, u2 r2) -> float {
      const float y0 = bflo(r0.x), y1 = bfhi(r0.x), y2 = bflo(r0.y),
                  y3 = bfhi(r0.y), y4 = bflo(r1.x), y5 = bfhi(r1.x),
                  y6 = bflo(r1.y), y7 = bfhi(r1.y), y8 = bflo(r2.x),
                  y9 = bfhi(r2.x), y10 = bflo(r2.y);
      float A = fmaf(y0, Wc2[0], bc);
      float B = y1 * Wc2[1];
      A = fmaf(y2, Wc2[2], A);   B = fmaf(y3, Wc2[3], B);
      A = fmaf(y4, Wc2[4], A);   B = fmaf(y5, Wc2[5], B);
      A = fmaf(y6, Wc2[6], A);   B = fmaf(y7, Wc2[7], B);
      A = fmaf(y8, Wc2[8], A);   B = fmaf(y9, Wc2[9], B);
      A = fmaf(y10, Wc2[10], A);
      return A + B;
    };

    float gi = GI(c0, c1, c2);

    int ao = (fwd ? 0 : (WD - 1) * ROW) + j;
    const int ad = fwd ? ROW : -ROW;

    float hj = 0.f, cj = 0.f;
    for (int t = 0; t < WD; ++t) {
      READLANES
      // prefetch row t+2 (off-chain)
      const int qc = q < 0 ? 0 : (q > qmax ? qmax : q);
      const u2 n0 = yv[qc], n1 = yv[qc + 1], n2 = yv[qc + 2];
      q += qd;
      UDOT(gi, g)
      STEP_TAIL(g)
      gi = GI(p0, p1, p2);  // input stage t+1 (off-chain)
      p0 = n0; p1 = n1; p2 = n2;
    }
  }
  __syncthreads();

  // ---- Phase E: writeout out[b][j][w] = acc[w*ROW+j] ----
  float* ob = out + (size_t)b * (NOUT * WD);
  for (int i = tid; i < NOUT * WD; i += 256) {
    const int jj = i >> 11;       // i / WD
    const int w = i & (WD - 1);   // i % WD
    ob[i] = acc[w * ROW + jj];
  }
}

extern "C" void kernel_launch(void* const* d_in, const int* in_sizes, int n_in,
                              void* d_out, int out_size, void* d_ws,
                              size_t ws_size, hipStream_t stream) {
  const float* x  = (const float*)d_in[0];
  const float* W0 = (const float*)d_in[1];
  const float* U0 = (const float*)d_in[2];
  const float* b0 = (const float*)d_in[3];
  const float* W1 = (const float*)d_in[4];
  const float* U1 = (const float*)d_in[5];
  const float* b1 = (const float*)d_in[6];
  float* out = (float*)d_out;

  mdlstm_fused<<<NB, 256, 0, stream>>>(x, W0, U0, b0, W1, U1, b1, out);
}

// Round 8
// 609.623 us; speedup vs baseline: 2.6949x; 1.2043x over previous
//
#include <hip/hip_runtime.h>
#include <hip/hip_bf16.h>

// 2-layer 4-direction MDLSTM, fused, one dispatch. B=256, Wd=2048, OUT=11.
// Quad lane layout + 12th dummy unit (zero weights -> h_11 == 0 exactly).
// R7: v_dot2_f32_f16 packed-pair dots (6 readlane + 6 fdot2 per dot),
// f16-pair y strip (L2 input = 6 fdot2, no unpack), exp2-folded activations,
// padded y strip (no per-step clamps). See R3/R4 rules: no LDS crossbar or
// scattered global atomics on the serial chain.

#define NOUT 11
#define WD 2048
#define NB 256
#define ROW 12
#define ACCN (WD * ROW)
#define YROW 6
#define YPAD 12
#define YBFN (WD * YROW + 2 * YPAD)

typedef float f2 __attribute__((ext_vector_type(2)));
typedef float f4 __attribute__((ext_vector_type(4)));
typedef unsigned int u32;
typedef u32 u32x2 __attribute__((ext_vector_type(2)));
typedef __fp16 h2 __attribute__((ext_vector_type(2)));

#define LOG2E 1.4426950408889634f

union UH { u32 u; h2 h; };
__device__ __forceinline__ u32 h2u(h2 v) { UH x; x.h = v; return x.u; }
__device__ __forceinline__ h2 u2h(u32 v) { UH x; x.u = v; return x.h; }

__device__ __forceinline__ h2 rlh(h2 v, int l) {
  return u2h((u32)__builtin_amdgcn_readlane((int)h2u(v), l));
}
template <int CTRL>
__device__ __forceinline__ float dppf(float v) {
  return __int_as_float(__builtin_amdgcn_update_dpp(
      __float_as_int(v), __float_as_int(v), CTRL, 0xF, 0xF, false));
}
__device__ __forceinline__ float rcp_(float x) { return __builtin_amdgcn_rcpf(x); }
__device__ __forceinline__ float exp2_(float x) { return __builtin_amdgcn_exp2f(x); }
__device__ __forceinline__ float dot2(h2 a, h2 b, float c) {
  return __builtin_amdgcn_fdot2(a, b, c, false);
}

// Variadic: __VA_ARGS__ is the off-chain PREP block (commas allowed).
#define STEP(...)                                                              \
  do {                                                                         \
    const float hnx = dppf<0x104>(hj); /* row_shl:4: lane i <- lane i+4 */     \
    const h2 hpk = __builtin_amdgcn_cvt_pkrtz(hj, hnx);                        \
    const h2 hp0 = rlh(hpk, 0);                                                \
    const h2 hp1 = rlh(hpk, 8);                                                \
    const h2 hp2 = rlh(hpk, 16);                                               \
    const h2 hp3 = rlh(hpk, 24);                                               \
    const h2 hp4 = rlh(hpk, 32);                                               \
    const h2 hp5 = rlh(hpk, 40);                                               \
    __VA_ARGS__                                                                \
    float ga = dot2(hp0, Up[0], gi);                                           \
    float gb = dot2(hp1, Up[1], 0.0f);                                         \
    ga = dot2(hp2, Up[2], ga);                                                 \
    gb = dot2(hp3, Up[3], gb);                                                 \
    ga = dot2(hp4, Up[4], ga);                                                 \
    gb = dot2(hp5, Up[5], gb);                                                 \
    const float g = ga + gb;                                                   \
    const float sg = rcp_(1.0f + exp2_(g));                                    \
    const float act = fmaf(kA, sg, kB);                                        \
    const float iv = dppf<0x00>(act);                                          \
    const float fv = dppf<0x55>(act);                                          \
    const float ov = dppf<0xAA>(act);                                          \
    const float av = dppf<0xFF>(act);                                          \
    cpr = fmaf(fv, cpr, iv * av);                                              \
    const float th = fmaf(2.0f, rcp_(1.0f + exp2_(cpr)), -1.0f);               \
    hj = ov * th;                                                              \
    if (cls == 0) atomicAdd(&acc[ao], hj);                                     \
    ao += ad;                                                                  \
  } while (0)

__global__ __launch_bounds__(256, 1) void mdlstm_fused(
    const float* __restrict__ x, const float* __restrict__ W0,
    const float* __restrict__ U0, const float* __restrict__ b0,
    const float* __restrict__ W1, const float* __restrict__ U1,
    const float* __restrict__ b1, float* __restrict__ out) {
  __shared__ __align__(16) float acc[ACCN];  // 96 KB
  __shared__ __align__(16) u32 ybf[YBFN];    // 48.1 KB (xw f32 | y f16-pairs)

  const int tid = threadIdx.x;
  const int b = blockIdx.x;
  float* xw = (float*)ybf;

  // ---- Phase A: height-sum x -> xw; zero acc ----
  {
    const f4* xb4 = (const f4*)(x + (size_t)b * 32 * WD);
    f4* xw4 = (f4*)xw;
    for (int w = tid; w < WD / 4; w += 256) {
      f4 s = xb4[w];
#pragma unroll
      for (int h = 1; h < 32; ++h) s += xb4[h * (WD / 4) + w];
      xw4[w] = s;
    }
    f4* a4 = (f4*)acc;
    const f4 z = {0.f, 0.f, 0.f, 0.f};
    for (int i = tid; i < ACCN / 4; i += 256) a4[i] = z;
  }
  __syncthreads();

  const int lane = tid & 63;
  const int d = tid >> 6;
  const bool fwd = ((d & 1) == 0);
  const int j = lane >> 2;   // unit (0..11; 11 = dummy)
  const int cls = lane & 3;  // 0=i 1=f_w 2=o 3=a
  const int colb = (cls == 0) ? 0 : (cls == 1) ? 11 : (cls == 2) ? 33 : 44;
  const int colc = (j < NOUT) ? (colb + j) : 54;
  const float scl =
      ((cls == 3) ? -2.0f * LOG2E : -LOG2E) * ((j < NOUT) ? 1.0f : 0.0f);
  const float kA = (cls == 3) ? (-4.0f * LOG2E) : 1.0f;
  const float kB = (cls == 3) ? (2.0f * LOG2E) : 0.0f;

  // ---- Phase B: layer-1 scan ----
  if (lane < 48) {
    float uv[12];
#pragma unroll
    for (int s = 0; s < NOUT; ++s) uv[s] = U0[(d * NOUT + s) * 55 + colc] * scl;
    uv[11] = 0.f;
    h2 Up[6];
#pragma unroll
    for (int k = 0; k < 6; ++k)
      Up[k] = __builtin_amdgcn_cvt_pkrtz(uv[2 * k], uv[2 * k + 1]);
    const float Wcs = W0[d * 55 + colc] * scl;
    const float bcs = b0[d * 55 + colc] * scl;

    int xo = fwd ? 0 : (WD - 1);
    const int xd = fwd ? 1 : -1;
    int ao = (fwd ? 0 : (WD - 1) * ROW) + j;
    const int ad = fwd ? ROW : -ROW;

    float hj = 0.f;
    float cpr = 0.f;
    float gi_next = 0.f;
    const float xc = xw[xo];
    xo += xd;
    float gi = fmaf(xc, Wcs, bcs);
    float xn = xw[xo & (WD - 1)];
    xo += xd;

    for (int t = 0; t < WD; ++t) {
      STEP(
        const float xn2 = xw[xo & (WD - 1)];  // prefetch t+2 (off-chain)
        xo += xd;
        gi_next = fmaf(xn, Wcs, bcs);         // input stage t+1
        xn = xn2;
      );
      gi = gi_next;
    }
  }
  __syncthreads();

  // ---- Phase C: pack acc -> f16-pair ybf (+ zero pads); re-zero acc ----
  {
    const f2* a2 = (const f2*)acc;
    for (int i = tid; i < WD * YROW; i += 256) {
      const f2 v = a2[i];
      ybf[YPAD + i] = h2u(__builtin_amdgcn_cvt_pkrtz(v.x, v.y));
    }
    if (tid < YPAD) {
      ybf[tid] = 0;
      ybf[WD * YROW + YPAD + tid] = 0;
    }
  }
  __syncthreads();
  {
    f4* a4 = (f4*)acc;
    const f4 z = {0.f, 0.f, 0.f, 0.f};
    for (int i = tid; i < ACCN / 4; i += 256) a4[i] = z;
  }
  __syncthreads();

  // ---- Phase D: layer-2 scan ----
  if (lane < 48) {
    float uv[12], wv[12];
#pragma unroll
    for (int s = 0; s < NOUT; ++s) {
      uv[s] = U1[(d * NOUT + s) * 55 + colc] * scl;
      wv[s] = W1[(d * NOUT + s) * 55 + colc] * scl;
    }
    uv[11] = 0.f;
    wv[11] = 0.f;
    h2 Up[6], Wp[6];
#pragma unroll
    for (int k = 0; k < 6; ++k) {
      Up[k] = __builtin_amdgcn_cvt_pkrtz(uv[2 * k], uv[2 * k + 1]);
      Wp[k] = __builtin_amdgcn_cvt_pkrtz(wv[2 * k], wv[2 * k + 1]);
    }
    const float bcs = b1[d * 55 + colc] * scl;

    const u32x2* yv = (const u32x2*)ybf;  // row r -> yv[3r+6 .. 3r+8]
    const int qd = fwd ? 3 : -3;
    int q = (fwd ? 0 : 3 * (WD - 1)) + 6;

    auto GI = [&](u32x2 r0, u32x2 r1, u32x2 r2) -> float {
      float A = dot2(u2h(r0.x), Wp[0], bcs);
      float B = dot2(u2h(r0.y), Wp[1], 0.f);
      A = dot2(u2h(r1.x), Wp[2], A);
      B = dot2(u2h(r1.y), Wp[3], B);
      A = dot2(u2h(r2.x), Wp[4], A);
      B = dot2(u2h(r2.y), Wp[5], B);
      return A + B;
    };

    u32x2 c0 = yv[q];
    u32x2 c1 = yv[q + 1];
    u32x2 c2 = yv[q + 2];
    q += qd;
    u32x2 p0 = yv[q];
    u32x2 p1 = yv[q + 1];
    u32x2 p2 = yv[q + 2];
    q += qd;

    float gi = GI(c0, c1, c2);

    int ao = (fwd ? 0 : (WD - 1) * ROW) + j;
    const int ad = fwd ? ROW : -ROW;

    float hj = 0.f;
    float cpr = 0.f;
    float gi_next = 0.f;
    for (int t = 0; t < WD; ++t) {
      STEP(
        const u32x2 n0 = yv[q];          // prefetch row t+2 (off-chain)
        const u32x2 n1 = yv[q + 1];
        const u32x2 n2 = yv[q + 2];
        q += qd;
        gi_next = GI(p0, p1, p2);        // input stage t+1
        p0 = n0; p1 = n1; p2 = n2;
      );
      gi = gi_next;
    }
  }
  __syncthreads();

  // ---- Phase E: writeout out[b][j][w] = acc[w*ROW+j] ----
  float* ob = out + (size_t)b * (NOUT * WD);
  for (int i = tid; i < NOUT * WD; i += 256) {
    const int jj = i >> 11;
    const int w = i & (WD - 1);
    ob[i] = acc[w * ROW + jj];
  }
}

extern "C" void kernel_launch(void* const* d_in, const int* in_sizes, int n_in,
                              void* d_out, int out_size, void* d_ws,
                              size_t ws_size, hipStream_t stream) {
  const float* x  = (const float*)d_in[0];
  const float* W0 = (const float*)d_in[1];
  const float* U0 = (const float*)d_in[2];
  const float* b0 = (const float*)d_in[3];
  const float* W1 = (const float*)d_in[4];
  const float* U1 = (const float*)d_in[5];
  const float* b1 = (const float*)d_in[6];
  float* out = (float*)d_out;

  mdlstm_fused<<<NB, 256, 0, stream>>>(x, W0, U0, b0, W1, U1, b1, out);
}